// Round 6
// baseline (259.813 us; speedup 1.0000x reference)
//
#include <hip/hip_runtime.h>

// inputs (8, 64, 16, 32, 32) fp32, embedding (512, 64) fp32
// N = 131072 positions, D = 64, K = 512
// d_out (fp32): [0, 8388608) quantized_st, [8388608] loss, [8388609, ...) indices
#define SPATIAL   16384
#define DIM       64
#define KCODES    512
#define NPOS      131072
#define QST_ELEMS 8388608
#define LOSS_OFF  8388608
#define IDX_OFF   8388609
#define NBLOCKS   (NPOS / 256)     // 512 blocks, 1 thread = 1 position

// --- non-contractable fp32 ops (match numpy's plain mul/add/sub) ---
__device__ __forceinline__ float mul_rn(float a, float b) {
#pragma clang fp contract(off)
    return a * b;
}
__device__ __forceinline__ float add_rn(float a, float b) {
#pragma clang fp contract(off)
    return a + b;
}
__device__ __forceinline__ float sub_rn(float a, float b) {
#pragma clang fp contract(off)
    return a - b;
}

// numpy pairwise_sum for n=64: 8 accumulators strided by 8, then
// ((r0+r1)+(r2+r3))+((r4+r5)+(r6+r7))
__device__ __forceinline__ float np_sumsq64(const float* v) {
    float r[8];
#pragma unroll
    for (int j = 0; j < 8; ++j) r[j] = mul_rn(v[j], v[j]);
#pragma unroll
    for (int i = 8; i < 64; i += 8) {
#pragma unroll
        for (int j = 0; j < 8; ++j) r[j] = add_rn(r[j], mul_rn(v[i + j], v[i + j]));
    }
    return add_rn(add_rn(add_rn(r[0], r[1]), add_rn(r[2], r[3])),
                  add_rn(add_rn(r[4], r[5]), add_rn(r[6], r[7])));
}

// e2[k] = np.sum(embedding**2, axis=1), bit-exact numpy pairwise order
__global__ void vq_e2_kernel(const float* __restrict__ emb, float* __restrict__ e2) {
    int k = threadIdx.x;
    if (k >= KCODES) return;
    float v[DIM];
#pragma unroll
    for (int d = 0; d < DIM; ++d) v[d] = emb[k * DIM + d];
    e2[k] = np_sumsq64(v);
}

// ---- x held in 16 NAMED float4s (no array -> no spill path) ----
#define DECLX float4 x0,x1,x2q,x3,x4,x5,x6,x7,x8,x9,x10,x11,x12,x13,x14,x15;

#define LOADX(v,q) \
    v.x = xin[(size_t)(4*(q)+0)*SPATIAL]; \
    v.y = xin[(size_t)(4*(q)+1)*SPATIAL]; \
    v.z = xin[(size_t)(4*(q)+2)*SPATIAL]; \
    v.w = xin[(size_t)(4*(q)+3)*SPATIAL];

// opaque pin: the asm output cannot be rematerialized -> the K-loop must
// consume these exact VGPR values instead of re-issuing the loads
#define PINQ(v) asm volatile("" : "+v"(v.x), "+v"(v.y), "+v"(v.z), "+v"(v.w));

// numpy 8-accumulator sumsq over named quads
#define SQA(ve,vo) \
    r0 = add_rn(r0, mul_rn(ve.x, ve.x)); r1 = add_rn(r1, mul_rn(ve.y, ve.y)); \
    r2 = add_rn(r2, mul_rn(ve.z, ve.z)); r3 = add_rn(r3, mul_rn(ve.w, ve.w)); \
    r4 = add_rn(r4, mul_rn(vo.x, vo.x)); r5 = add_rn(r5, mul_rn(vo.y, vo.y)); \
    r6 = add_rn(r6, mul_rn(vo.z, vo.z)); r7 = add_rn(r7, mul_rn(vo.w, vo.w));

// two interleaved serial-ascending-d FMA chains (codes a and b); e-operands
// come from BLOCK-UNIFORM pointers -> s_load + v_fma(v,s,v) scalar path
#define DSTEP(v,q) { \
    acca = __builtin_fmaf(v.x, ea[4*(q)+0], acca); accb = __builtin_fmaf(v.x, eb[4*(q)+0], accb); \
    acca = __builtin_fmaf(v.y, ea[4*(q)+1], acca); accb = __builtin_fmaf(v.y, eb[4*(q)+1], accb); \
    acca = __builtin_fmaf(v.z, ea[4*(q)+2], acca); accb = __builtin_fmaf(v.z, eb[4*(q)+2], accb); \
    acca = __builtin_fmaf(v.w, ea[4*(q)+3], acca); accb = __builtin_fmaf(v.w, eb[4*(q)+3], accb); }

#define EPIQ(v,q) { \
    float4 e4 = eq4[q]; \
    float dd; \
    dd = sub_rn(e4.x, v.x); oq[(size_t)(4*(q)+0)*SPATIAL] = add_rn(v.x, dd); lsum += (double)mul_rn(dd, dd); \
    dd = sub_rn(e4.y, v.y); oq[(size_t)(4*(q)+1)*SPATIAL] = add_rn(v.y, dd); lsum += (double)mul_rn(dd, dd); \
    dd = sub_rn(e4.z, v.z); oq[(size_t)(4*(q)+2)*SPATIAL] = add_rn(v.z, dd); lsum += (double)mul_rn(dd, dd); \
    dd = sub_rn(e4.w, v.w); oq[(size_t)(4*(q)+3)*SPATIAL] = add_rn(v.w, dd); lsum += (double)mul_rn(dd, dd); }

__global__ __launch_bounds__(256, 2) void vq_main_kernel(
        const float* __restrict__ in, const float* __restrict__ emb,
        const float* __restrict__ e2, float* __restrict__ out,
        double* __restrict__ losspart) {
    __shared__ double lpart[4];

    const int t = threadIdx.x;
    const int p = blockIdx.x * 256 + t;       // this thread's position
    const int b = p >> 14;
    const int s = p & 16383;
    const float* xin = in + (size_t)b * (DIM * SPATIAL) + s;

    DECLX
    LOADX(x0, 0)  LOADX(x1, 1)  LOADX(x2q, 2) LOADX(x3, 3)
    LOADX(x4, 4)  LOADX(x5, 5)  LOADX(x6, 6)  LOADX(x7, 7)
    LOADX(x8, 8)  LOADX(x9, 9)  LOADX(x10,10) LOADX(x11,11)
    LOADX(x12,12) LOADX(x13,13) LOADX(x14,14) LOADX(x15,15)

    PINQ(x0)  PINQ(x1)  PINQ(x2q) PINQ(x3)
    PINQ(x4)  PINQ(x5)  PINQ(x6)  PINQ(x7)
    PINQ(x8)  PINQ(x9)  PINQ(x10) PINQ(x11)
    PINQ(x12) PINQ(x13) PINQ(x14) PINQ(x15)

    // x2 = np.sum(flat**2) in numpy pairwise order (from pinned values)
    float r0 = mul_rn(x0.x, x0.x), r1 = mul_rn(x0.y, x0.y);
    float r2 = mul_rn(x0.z, x0.z), r3 = mul_rn(x0.w, x0.w);
    float r4 = mul_rn(x1.x, x1.x), r5 = mul_rn(x1.y, x1.y);
    float r6 = mul_rn(x1.z, x1.z), r7 = mul_rn(x1.w, x1.w);
    SQA(x2q, x3) SQA(x4, x5) SQA(x6, x7) SQA(x8, x9)
    SQA(x10, x11) SQA(x12, x13) SQA(x14, x15)
    const float x2 = add_rn(add_rn(add_rn(r0, r1), add_rn(r2, r3)),
                            add_rn(add_rn(r4, r5), add_rn(r6, r7)));

    // distance scan: ALL threads walk k ascending (block-uniform addresses)
    float best = __builtin_inff();
    int bidx = 0;
#pragma unroll 1
    for (int kk = 0; kk < KCODES; kk += 2) {
        const float* ea = emb + (size_t)kk * DIM;   // uniform -> s_load
        const float* eb = ea + DIM;
        float acca = 0.0f, accb = 0.0f;
        DSTEP(x0, 0)  DSTEP(x1, 1)  DSTEP(x2q, 2) DSTEP(x3, 3)
        DSTEP(x4, 4)  DSTEP(x5, 5)  DSTEP(x6, 6)  DSTEP(x7, 7)
        DSTEP(x8, 8)  DSTEP(x9, 9)  DSTEP(x10,10) DSTEP(x11,11)
        DSTEP(x12,12) DSTEP(x13,13) DSTEP(x14,14) DSTEP(x15,15)
        float dista = sub_rn(add_rn(x2, e2[kk]),     mul_rn(2.0f, acca));
        float distb = sub_rn(add_rn(x2, e2[kk + 1]), mul_rn(2.0f, accb));
        if (dista < best) { best = dista; bidx = kk; }
        if (distb < best) { best = distb; bidx = kk + 1; }
    }

    out[IDX_OFF + p] = (float)bidx;

    // epilogue: qst + loss from registers; codebook row gather is cache-hot
    const float4* eq4 = (const float4*)(emb + (size_t)bidx * DIM);
    float* oq = out + (size_t)b * (DIM * SPATIAL) + s;
    double lsum = 0.0;
    EPIQ(x0, 0)  EPIQ(x1, 1)  EPIQ(x2q, 2) EPIQ(x3, 3)
    EPIQ(x4, 4)  EPIQ(x5, 5)  EPIQ(x6, 6)  EPIQ(x7, 7)
    EPIQ(x8, 8)  EPIQ(x9, 9)  EPIQ(x10,10) EPIQ(x11,11)
    EPIQ(x12,12) EPIQ(x13,13) EPIQ(x14,14) EPIQ(x15,15)

    // deterministic loss partial: wave shuffle reduce -> ordered 4-wave sum
#pragma unroll
    for (int off = 32; off > 0; off >>= 1) lsum += __shfl_down(lsum, off, 64);
    const int lane = t & 63, wave = t >> 6;
    if (lane == 0) lpart[wave] = lsum;
    __syncthreads();
    if (t == 0) losspart[blockIdx.x] = ((lpart[0] + lpart[1]) + lpart[2]) + lpart[3];
}

// reduce 512 block partials (deterministic fixed-order tree) -> loss scalar
__global__ void vq_finalize_kernel(const double* __restrict__ part,
                                   float* __restrict__ out) {
    __shared__ double sdata[256];
    int t = threadIdx.x;
    sdata[t] = part[t] + part[t + 256];
    __syncthreads();
    for (int stride = 128; stride > 0; stride >>= 1) {
        if (t < stride) sdata[t] = sdata[t] + sdata[t + stride];
        __syncthreads();
    }
    if (t == 0) {
        double m = sdata[0] / (double)QST_ELEMS;
        float mf = (float)m;
        out[LOSS_OFF] = add_rn(mf, mul_rn(0.25f, mf));
    }
}

extern "C" void kernel_launch(void* const* d_in, const int* in_sizes, int n_in,
                              void* d_out, int out_size, void* d_ws, size_t ws_size,
                              hipStream_t stream) {
    const float* in  = (const float*)d_in[0];
    const float* emb = (const float*)d_in[1];
    float* out = (float*)d_out;
    double* losspart = (double*)d_ws;                              // 512 doubles
    float* e2 = (float*)((char*)d_ws + NBLOCKS * sizeof(double));  // 512 floats

    vq_e2_kernel<<<1, KCODES, 0, stream>>>(emb, e2);
    vq_main_kernel<<<NBLOCKS, 256, 0, stream>>>(in, emb, e2, out, losspart);
    vq_finalize_kernel<<<1, 256, 0, stream>>>(losspart, out);
}

// Round 7
// 258.992 us; speedup vs baseline: 1.0032x; 1.0032x over previous
//
#include <hip/hip_runtime.h>

// inputs (8, 64, 16, 32, 32) fp32, embedding (512, 64) fp32
// N = 131072 positions, D = 64, K = 512
// d_out (fp32): [0, 8388608) quantized_st, [8388608] loss, [8388609, ...) indices
#define SPATIAL   16384
#define DIM       64
#define KCODES    512
#define NPOS      131072
#define QST_ELEMS 8388608
#define LOSS_OFF  8388608
#define IDX_OFF   8388609
#define NBLOCKS   (NPOS / 256)     // 512 blocks, 1 thread = 1 position

// --- non-contractable fp32 ops (match numpy's plain mul/add/sub) ---
__device__ __forceinline__ float mul_rn(float a, float b) {
#pragma clang fp contract(off)
    return a * b;
}
__device__ __forceinline__ float add_rn(float a, float b) {
#pragma clang fp contract(off)
    return a + b;
}
__device__ __forceinline__ float sub_rn(float a, float b) {
#pragma clang fp contract(off)
    return a - b;
}

// numpy pairwise_sum for n=64: 8 accumulators strided by 8, then
// ((r0+r1)+(r2+r3))+((r4+r5)+(r6+r7))
__device__ __forceinline__ float np_sumsq64(const float* v) {
    float r[8];
#pragma unroll
    for (int j = 0; j < 8; ++j) r[j] = mul_rn(v[j], v[j]);
#pragma unroll
    for (int i = 8; i < 64; i += 8) {
#pragma unroll
        for (int j = 0; j < 8; ++j) r[j] = add_rn(r[j], mul_rn(v[i + j], v[i + j]));
    }
    return add_rn(add_rn(add_rn(r[0], r[1]), add_rn(r[2], r[3])),
                  add_rn(add_rn(r[4], r[5]), add_rn(r[6], r[7])));
}

// e2[k] = np.sum(embedding**2, axis=1), bit-exact numpy pairwise order
__global__ void vq_e2_kernel(const float* __restrict__ emb, float* __restrict__ e2) {
    int k = blockIdx.x * 64 + threadIdx.x;
    if (k >= KCODES) return;
    float v[DIM];
#pragma unroll
    for (int d = 0; d < DIM; ++d) v[d] = emb[k * DIM + d];
    e2[k] = np_sumsq64(v);
}

// ---- x held in 16 NAMED float4s (no array -> no spill path) ----
#define DECLX float4 x0,x1,x2q,x3,x4,x5,x6,x7,x8,x9,x10,x11,x12,x13,x14,x15;

#define LOADX(v,q) \
    v.x = xin[(size_t)(4*(q)+0)*SPATIAL]; \
    v.y = xin[(size_t)(4*(q)+1)*SPATIAL]; \
    v.z = xin[(size_t)(4*(q)+2)*SPATIAL]; \
    v.w = xin[(size_t)(4*(q)+3)*SPATIAL];

// opaque pin: the asm output cannot be rematerialized -> the K-loop must
// consume these exact VGPR values instead of re-issuing the loads
#define PINQ(v) asm volatile("" : "+v"(v.x), "+v"(v.y), "+v"(v.z), "+v"(v.w));

// numpy 8-accumulator sumsq over named quads
#define SQA(ve,vo) \
    r0 = add_rn(r0, mul_rn(ve.x, ve.x)); r1 = add_rn(r1, mul_rn(ve.y, ve.y)); \
    r2 = add_rn(r2, mul_rn(ve.z, ve.z)); r3 = add_rn(r3, mul_rn(ve.w, ve.w)); \
    r4 = add_rn(r4, mul_rn(vo.x, vo.x)); r5 = add_rn(r5, mul_rn(vo.y, vo.y)); \
    r6 = add_rn(r6, mul_rn(vo.z, vo.z)); r7 = add_rn(r7, mul_rn(vo.w, vo.w));

// two interleaved serial-ascending-d FMA chains (codes a and b); e-operands
// come from BLOCK-UNIFORM pointers -> s_load + v_fma(v,s,v) scalar path
#define DSTEP(v,q) { \
    acca = __builtin_fmaf(v.x, ea[4*(q)+0], acca); accb = __builtin_fmaf(v.x, eb[4*(q)+0], accb); \
    acca = __builtin_fmaf(v.y, ea[4*(q)+1], acca); accb = __builtin_fmaf(v.y, eb[4*(q)+1], accb); \
    acca = __builtin_fmaf(v.z, ea[4*(q)+2], acca); accb = __builtin_fmaf(v.z, eb[4*(q)+2], accb); \
    acca = __builtin_fmaf(v.w, ea[4*(q)+3], acca); accb = __builtin_fmaf(v.w, eb[4*(q)+3], accb); }

#define EPIQ(v,q) { \
    float4 e4 = eq4[q]; \
    float dd; \
    dd = sub_rn(e4.x, v.x); oq[(size_t)(4*(q)+0)*SPATIAL] = add_rn(v.x, dd); lsum += (double)mul_rn(dd, dd); \
    dd = sub_rn(e4.y, v.y); oq[(size_t)(4*(q)+1)*SPATIAL] = add_rn(v.y, dd); lsum += (double)mul_rn(dd, dd); \
    dd = sub_rn(e4.z, v.z); oq[(size_t)(4*(q)+2)*SPATIAL] = add_rn(v.z, dd); lsum += (double)mul_rn(dd, dd); \
    dd = sub_rn(e4.w, v.w); oq[(size_t)(4*(q)+3)*SPATIAL] = add_rn(v.w, dd); lsum += (double)mul_rn(dd, dd); }

// KEY CHANGE vs R6: amdgpu_waves_per_eu(2,2) pins the backend's occupancy
// TARGET (launch_bounds' 2nd arg is only a floor; the scheduler still chased
// max occupancy and spilled x to scratch -> VGPR=48, ~250us of L2 spill
// traffic).  Grid supplies only 2 waves/SIMD anyway, so max=2 costs nothing
// and gives the allocator a 256-VGPR budget it will actually use.
__global__ __launch_bounds__(256)
__attribute__((amdgpu_waves_per_eu(2, 2)))
void vq_main_kernel(
        const float* __restrict__ in, const float* __restrict__ emb,
        const float* __restrict__ e2, float* __restrict__ out,
        double* __restrict__ losspart) {
    __shared__ double lpart[4];

    const int t = threadIdx.x;
    const int p = blockIdx.x * 256 + t;       // this thread's position
    const int b = p >> 14;
    const int s = p & 16383;
    const float* xin = in + (size_t)b * (DIM * SPATIAL) + s;

    DECLX
    LOADX(x0, 0)  LOADX(x1, 1)  LOADX(x2q, 2) LOADX(x3, 3)
    LOADX(x4, 4)  LOADX(x5, 5)  LOADX(x6, 6)  LOADX(x7, 7)
    LOADX(x8, 8)  LOADX(x9, 9)  LOADX(x10,10) LOADX(x11,11)
    LOADX(x12,12) LOADX(x13,13) LOADX(x14,14) LOADX(x15,15)

    PINQ(x0)  PINQ(x1)  PINQ(x2q) PINQ(x3)
    PINQ(x4)  PINQ(x5)  PINQ(x6)  PINQ(x7)
    PINQ(x8)  PINQ(x9)  PINQ(x10) PINQ(x11)
    PINQ(x12) PINQ(x13) PINQ(x14) PINQ(x15)

    // x2 = np.sum(flat**2) in numpy pairwise order (from pinned values)
    float r0 = mul_rn(x0.x, x0.x), r1 = mul_rn(x0.y, x0.y);
    float r2 = mul_rn(x0.z, x0.z), r3 = mul_rn(x0.w, x0.w);
    float r4 = mul_rn(x1.x, x1.x), r5 = mul_rn(x1.y, x1.y);
    float r6 = mul_rn(x1.z, x1.z), r7 = mul_rn(x1.w, x1.w);
    SQA(x2q, x3) SQA(x4, x5) SQA(x6, x7) SQA(x8, x9)
    SQA(x10, x11) SQA(x12, x13) SQA(x14, x15)
    const float x2 = add_rn(add_rn(add_rn(r0, r1), add_rn(r2, r3)),
                            add_rn(add_rn(r4, r5), add_rn(r6, r7)));

    // distance scan: ALL threads walk k ascending (block-uniform addresses)
    float best = __builtin_inff();
    int bidx = 0;
#pragma unroll 1
    for (int kk = 0; kk < KCODES; kk += 2) {
        const float* ea = emb + (size_t)kk * DIM;   // uniform -> s_load
        const float* eb = ea + DIM;
        float acca = 0.0f, accb = 0.0f;
        DSTEP(x0, 0)  DSTEP(x1, 1)  DSTEP(x2q, 2) DSTEP(x3, 3)
        DSTEP(x4, 4)  DSTEP(x5, 5)  DSTEP(x6, 6)  DSTEP(x7, 7)
        DSTEP(x8, 8)  DSTEP(x9, 9)  DSTEP(x10,10) DSTEP(x11,11)
        DSTEP(x12,12) DSTEP(x13,13) DSTEP(x14,14) DSTEP(x15,15)
        float dista = sub_rn(add_rn(x2, e2[kk]),     mul_rn(2.0f, acca));
        float distb = sub_rn(add_rn(x2, e2[kk + 1]), mul_rn(2.0f, accb));
        if (dista < best) { best = dista; bidx = kk; }
        if (distb < best) { best = distb; bidx = kk + 1; }
    }

    out[IDX_OFF + p] = (float)bidx;

    // epilogue: qst + loss from registers; codebook row gather is cache-hot
    const float4* eq4 = (const float4*)(emb + (size_t)bidx * DIM);
    float* oq = out + (size_t)b * (DIM * SPATIAL) + s;
    double lsum = 0.0;
    EPIQ(x0, 0)  EPIQ(x1, 1)  EPIQ(x2q, 2) EPIQ(x3, 3)
    EPIQ(x4, 4)  EPIQ(x5, 5)  EPIQ(x6, 6)  EPIQ(x7, 7)
    EPIQ(x8, 8)  EPIQ(x9, 9)  EPIQ(x10,10) EPIQ(x11,11)
    EPIQ(x12,12) EPIQ(x13,13) EPIQ(x14,14) EPIQ(x15,15)

    // deterministic loss partial: wave shuffle reduce -> ordered 4-wave sum
#pragma unroll
    for (int off = 32; off > 0; off >>= 1) lsum += __shfl_down(lsum, off, 64);
    const int lane = t & 63, wave = t >> 6;
    if (lane == 0) lpart[wave] = lsum;
    __syncthreads();
    if (t == 0) losspart[blockIdx.x] = ((lpart[0] + lpart[1]) + lpart[2]) + lpart[3];
}

// reduce 512 block partials (deterministic fixed-order tree) -> loss scalar
__global__ void vq_finalize_kernel(const double* __restrict__ part,
                                   float* __restrict__ out) {
    __shared__ double sdata[256];
    int t = threadIdx.x;
    sdata[t] = part[t] + part[t + 256];
    __syncthreads();
    for (int stride = 128; stride > 0; stride >>= 1) {
        if (t < stride) sdata[t] = sdata[t] + sdata[t + stride];
        __syncthreads();
    }
    if (t == 0) {
        double m = sdata[0] / (double)QST_ELEMS;
        float mf = (float)m;
        out[LOSS_OFF] = add_rn(mf, mul_rn(0.25f, mf));
    }
}

extern "C" void kernel_launch(void* const* d_in, const int* in_sizes, int n_in,
                              void* d_out, int out_size, void* d_ws, size_t ws_size,
                              hipStream_t stream) {
    const float* in  = (const float*)d_in[0];
    const float* emb = (const float*)d_in[1];
    float* out = (float*)d_out;
    double* losspart = (double*)d_ws;                              // 512 doubles
    float* e2 = (float*)((char*)d_ws + NBLOCKS * sizeof(double));  // 512 floats

    vq_e2_kernel<<<KCODES / 64, 64, 0, stream>>>(emb, e2);
    vq_main_kernel<<<NBLOCKS, 256, 0, stream>>>(in, emb, e2, out, losspart);
    vq_finalize_kernel<<<1, 256, 0, stream>>>(losspart, out);
}

// Round 8
// 172.804 us; speedup vs baseline: 1.5035x; 1.4988x over previous
//
#include <hip/hip_runtime.h>

// inputs (8, 64, 16, 32, 32) fp32, embedding (512, 64) fp32
// N = 131072 positions, D = 64, K = 512
// d_out (fp32): [0, 8388608) quantized_st, [8388608] loss, [8388609, ...) indices
#define SPATIAL   16384
#define DIM       64
#define KCODES    512
#define NPOS      131072
#define QST_ELEMS 8388608
#define LOSS_OFF  8388608
#define IDX_OFF   8388609

#define NSPLIT    4                  // k-slices (across blocks)
#define KPS       (KCODES / NSPLIT)  // 128 codes per slice
#define PTILES    (NPOS / 256)       // 512 position tiles

// workspace layout
#define WS_LOSS   0                                    // 512 doubles
#define WS_E2     4096                                 // 512 floats
#define WS_PD     8192                                 // NPOS*NSPLIT floats = 2 MB
#define WS_PI     (WS_PD + NPOS * NSPLIT * 4)          // NPOS*NSPLIT ints   = 2 MB
#define WS_NEED   (WS_PI + NPOS * NSPLIT * 4)

// --- non-contractable fp32 ops (match numpy's plain mul/add/sub) ---
__device__ __forceinline__ float mul_rn(float a, float b) {
#pragma clang fp contract(off)
    return a * b;
}
__device__ __forceinline__ float add_rn(float a, float b) {
#pragma clang fp contract(off)
    return a + b;
}
__device__ __forceinline__ float sub_rn(float a, float b) {
#pragma clang fp contract(off)
    return a - b;
}

// numpy pairwise_sum for n=64: 8 accumulators strided by 8, then
// ((r0+r1)+(r2+r3))+((r4+r5)+(r6+r7))
__device__ __forceinline__ float np_sumsq64(const float* v) {
    float r[8];
#pragma unroll
    for (int j = 0; j < 8; ++j) r[j] = mul_rn(v[j], v[j]);
#pragma unroll
    for (int i = 8; i < 64; i += 8) {
#pragma unroll
        for (int j = 0; j < 8; ++j) r[j] = add_rn(r[j], mul_rn(v[i + j], v[i + j]));
    }
    return add_rn(add_rn(add_rn(r[0], r[1]), add_rn(r[2], r[3])),
                  add_rn(add_rn(r[4], r[5]), add_rn(r[6], r[7])));
}

// e2[k] = np.sum(embedding**2, axis=1), bit-exact numpy pairwise order
__global__ void vq_e2_kernel(const float* __restrict__ emb, float* __restrict__ e2) {
    int k = blockIdx.x * 64 + threadIdx.x;
    if (k >= KCODES) return;
    float v[DIM];
#pragma unroll
    for (int d = 0; d < DIM; ++d) v[d] = emb[k * DIM + d];
    e2[k] = np_sumsq64(v);
}

// ---- x held in 16 NAMED float4s ----
#define DECLX float4 x0,x1,x2q,x3,x4,x5,x6,x7,x8,x9,x10,x11,x12,x13,x14,x15;

#define LOADX(v,q) \
    v.x = xin[(size_t)(4*(q)+0)*SPATIAL]; \
    v.y = xin[(size_t)(4*(q)+1)*SPATIAL]; \
    v.z = xin[(size_t)(4*(q)+2)*SPATIAL]; \
    v.w = xin[(size_t)(4*(q)+3)*SPATIAL];

#define PINQ(v) asm volatile("" : "+v"(v.x), "+v"(v.y), "+v"(v.z), "+v"(v.w));

#define SQA(ve,vo) \
    r0 = add_rn(r0, mul_rn(ve.x, ve.x)); r1 = add_rn(r1, mul_rn(ve.y, ve.y)); \
    r2 = add_rn(r2, mul_rn(ve.z, ve.z)); r3 = add_rn(r3, mul_rn(ve.w, ve.w)); \
    r4 = add_rn(r4, mul_rn(vo.x, vo.x)); r5 = add_rn(r5, mul_rn(vo.y, vo.y)); \
    r6 = add_rn(r6, mul_rn(vo.z, vo.z)); r7 = add_rn(r7, mul_rn(vo.w, vo.w));

#define DSTEP(v,q) { \
    acca = __builtin_fmaf(v.x, ea[4*(q)+0], acca); accb = __builtin_fmaf(v.x, eb[4*(q)+0], accb); \
    acca = __builtin_fmaf(v.y, ea[4*(q)+1], acca); accb = __builtin_fmaf(v.y, eb[4*(q)+1], accb); \
    acca = __builtin_fmaf(v.z, ea[4*(q)+2], acca); accb = __builtin_fmaf(v.z, eb[4*(q)+2], accb); \
    acca = __builtin_fmaf(v.w, ea[4*(q)+3], acca); accb = __builtin_fmaf(v.w, eb[4*(q)+3], accb); }

#define SUMSQ_X2 \
    float r0 = mul_rn(x0.x, x0.x), r1 = mul_rn(x0.y, x0.y); \
    float r2 = mul_rn(x0.z, x0.z), r3 = mul_rn(x0.w, x0.w); \
    float r4 = mul_rn(x1.x, x1.x), r5 = mul_rn(x1.y, x1.y); \
    float r6 = mul_rn(x1.z, x1.z), r7 = mul_rn(x1.w, x1.w); \
    SQA(x2q, x3) SQA(x4, x5) SQA(x6, x7) SQA(x8, x9) \
    SQA(x10, x11) SQA(x12, x13) SQA(x14, x15) \
    const float x2 = add_rn(add_rn(add_rn(r0, r1), add_rn(r2, r3)), \
                            add_rn(add_rn(r4, r5), add_rn(r6, r7)));

// ---------------------------------------------------------------------------
// Pass 1: distance scan, K split across blocks (k-base from blockIdx ->
// uniform BY CONSTRUCTION -> scalar s_load path for e; x pinned in VGPRs).
// Grid = NSPLIT * PTILES blocks of 256 -> 8192 waves -> 4-5 waves/SIMD to
// hide the chunked-SMEM stalls that capped R4-R7 at 2 waves/SIMD.
// ---------------------------------------------------------------------------
__global__ __launch_bounds__(256)
__attribute__((amdgpu_waves_per_eu(4, 4)))
void vq_scan_kernel(const float* __restrict__ in, const float* __restrict__ emb,
                    const float* __restrict__ e2,
                    float* __restrict__ pd, int* __restrict__ pi) {
    const int t  = threadIdx.x;
    const int jr = blockIdx.x >> 9;          // 0..3  k-slice
    const int pt = blockIdx.x & (PTILES - 1);
    const int p  = pt * 256 + t;
    const int b  = p >> 14;
    const int s  = p & 16383;
    const float* xin = in + (size_t)b * (DIM * SPATIAL) + s;

    DECLX
    LOADX(x0, 0)  LOADX(x1, 1)  LOADX(x2q, 2) LOADX(x3, 3)
    LOADX(x4, 4)  LOADX(x5, 5)  LOADX(x6, 6)  LOADX(x7, 7)
    LOADX(x8, 8)  LOADX(x9, 9)  LOADX(x10,10) LOADX(x11,11)
    LOADX(x12,12) LOADX(x13,13) LOADX(x14,14) LOADX(x15,15)

    PINQ(x0)  PINQ(x1)  PINQ(x2q) PINQ(x3)
    PINQ(x4)  PINQ(x5)  PINQ(x6)  PINQ(x7)
    PINQ(x8)  PINQ(x9)  PINQ(x10) PINQ(x11)
    PINQ(x12) PINQ(x13) PINQ(x14) PINQ(x15)

    SUMSQ_X2

    const int kbase = jr * KPS;              // SGPR (from blockIdx)
    float best = __builtin_inff();
    int bidx = kbase;
#pragma unroll 1
    for (int kk = 0; kk < KPS; kk += 2) {
        const float* ea = emb + (size_t)(kbase + kk) * DIM;   // uniform -> s_load
        const float* eb = ea + DIM;
        float acca = 0.0f, accb = 0.0f;
        DSTEP(x0, 0)  DSTEP(x1, 1)  DSTEP(x2q, 2) DSTEP(x3, 3)
        DSTEP(x4, 4)  DSTEP(x5, 5)  DSTEP(x6, 6)  DSTEP(x7, 7)
        DSTEP(x8, 8)  DSTEP(x9, 9)  DSTEP(x10,10) DSTEP(x11,11)
        DSTEP(x12,12) DSTEP(x13,13) DSTEP(x14,14) DSTEP(x15,15)
        float dista = sub_rn(add_rn(x2, e2[kbase + kk]),     mul_rn(2.0f, acca));
        float distb = sub_rn(add_rn(x2, e2[kbase + kk + 1]), mul_rn(2.0f, accb));
        if (dista < best) { best = dista; bidx = kbase + kk; }
        if (distb < best) { best = distb; bidx = kbase + kk + 1; }
    }

    pd[(size_t)jr * NPOS + p] = best;
    pi[(size_t)jr * NPOS + p] = bidx;
}

// ---------------------------------------------------------------------------
// Pass 2: combine 4 partials (ascending k-slice, strict < == global first-min),
// gather code row, write idx + qst, accumulate deterministic loss partials.
// ---------------------------------------------------------------------------
__global__ __launch_bounds__(256)
void vq_epilogue_kernel(const float* __restrict__ in, const float* __restrict__ emb,
                        const float* __restrict__ pd, const int* __restrict__ pi,
                        float* __restrict__ out, double* __restrict__ losspart) {
    __shared__ double lpart[4];
    const int t = threadIdx.x;
    const int p = blockIdx.x * 256 + t;
    const int b = p >> 14;
    const int s = p & 16383;

    float fb = pd[p];
    int   fi = pi[p];
#pragma unroll
    for (int j = 1; j < NSPLIT; ++j) {
        float dv = pd[(size_t)j * NPOS + p];
        int   iv = pi[(size_t)j * NPOS + p];
        if (dv < fb) { fb = dv; fi = iv; }
    }

    out[IDX_OFF + p] = (float)fi;

    const float4* eq4 = (const float4*)(emb + (size_t)fi * DIM);  // L2-hot gather
    const float* xin = in + (size_t)b * (DIM * SPATIAL) + s;
    float* oq = out + (size_t)b * (DIM * SPATIAL) + s;
    double lsum = 0.0;
#pragma unroll
    for (int q = 0; q < 16; ++q) {
        float4 e4 = eq4[q];
        float ev[4] = {e4.x, e4.y, e4.z, e4.w};
#pragma unroll
        for (int c = 0; c < 4; ++c) {
            const int d = 4 * q + c;
            float xv = xin[(size_t)d * SPATIAL];
            float dd = sub_rn(ev[c], xv);              // fl(q - x)
            oq[(size_t)d * SPATIAL] = add_rn(xv, dd);  // fl(x + fl(q - x))
            lsum += (double)mul_rn(dd, dd);
        }
    }

    // deterministic loss partial: wave shuffle reduce -> ordered 4-wave sum
#pragma unroll
    for (int off = 32; off > 0; off >>= 1) lsum += __shfl_down(lsum, off, 64);
    const int lane = t & 63, wave = t >> 6;
    if (lane == 0) lpart[wave] = lsum;
    __syncthreads();
    if (t == 0) losspart[blockIdx.x] = ((lpart[0] + lpart[1]) + lpart[2]) + lpart[3];
}

// ---------------------------------------------------------------------------
// Fallback fused kernel (R7 path) if ws_size is too small for partials.
// ---------------------------------------------------------------------------
#define EPIQ(v,q) { \
    float4 e4 = eq4[q]; \
    float dd; \
    dd = sub_rn(e4.x, v.x); oq[(size_t)(4*(q)+0)*SPATIAL] = add_rn(v.x, dd); lsum += (double)mul_rn(dd, dd); \
    dd = sub_rn(e4.y, v.y); oq[(size_t)(4*(q)+1)*SPATIAL] = add_rn(v.y, dd); lsum += (double)mul_rn(dd, dd); \
    dd = sub_rn(e4.z, v.z); oq[(size_t)(4*(q)+2)*SPATIAL] = add_rn(v.z, dd); lsum += (double)mul_rn(dd, dd); \
    dd = sub_rn(e4.w, v.w); oq[(size_t)(4*(q)+3)*SPATIAL] = add_rn(v.w, dd); lsum += (double)mul_rn(dd, dd); }

__global__ __launch_bounds__(256)
__attribute__((amdgpu_waves_per_eu(2, 2)))
void vq_fused_kernel(const float* __restrict__ in, const float* __restrict__ emb,
                     const float* __restrict__ e2, float* __restrict__ out,
                     double* __restrict__ losspart) {
    __shared__ double lpart[4];
    const int t = threadIdx.x;
    const int p = blockIdx.x * 256 + t;
    const int b = p >> 14;
    const int s = p & 16383;
    const float* xin = in + (size_t)b * (DIM * SPATIAL) + s;

    DECLX
    LOADX(x0, 0)  LOADX(x1, 1)  LOADX(x2q, 2) LOADX(x3, 3)
    LOADX(x4, 4)  LOADX(x5, 5)  LOADX(x6, 6)  LOADX(x7, 7)
    LOADX(x8, 8)  LOADX(x9, 9)  LOADX(x10,10) LOADX(x11,11)
    LOADX(x12,12) LOADX(x13,13) LOADX(x14,14) LOADX(x15,15)
    PINQ(x0)  PINQ(x1)  PINQ(x2q) PINQ(x3)
    PINQ(x4)  PINQ(x5)  PINQ(x6)  PINQ(x7)
    PINQ(x8)  PINQ(x9)  PINQ(x10) PINQ(x11)
    PINQ(x12) PINQ(x13) PINQ(x14) PINQ(x15)
    SUMSQ_X2

    float best = __builtin_inff();
    int bidx = 0;
#pragma unroll 1
    for (int kk = 0; kk < KCODES; kk += 2) {
        const float* ea = emb + (size_t)kk * DIM;
        const float* eb = ea + DIM;
        float acca = 0.0f, accb = 0.0f;
        DSTEP(x0, 0)  DSTEP(x1, 1)  DSTEP(x2q, 2) DSTEP(x3, 3)
        DSTEP(x4, 4)  DSTEP(x5, 5)  DSTEP(x6, 6)  DSTEP(x7, 7)
        DSTEP(x8, 8)  DSTEP(x9, 9)  DSTEP(x10,10) DSTEP(x11,11)
        DSTEP(x12,12) DSTEP(x13,13) DSTEP(x14,14) DSTEP(x15,15)
        float dista = sub_rn(add_rn(x2, e2[kk]),     mul_rn(2.0f, acca));
        float distb = sub_rn(add_rn(x2, e2[kk + 1]), mul_rn(2.0f, accb));
        if (dista < best) { best = dista; bidx = kk; }
        if (distb < best) { best = distb; bidx = kk + 1; }
    }

    out[IDX_OFF + p] = (float)bidx;
    const float4* eq4 = (const float4*)(emb + (size_t)bidx * DIM);
    float* oq = out + (size_t)b * (DIM * SPATIAL) + s;
    double lsum = 0.0;
    EPIQ(x0, 0)  EPIQ(x1, 1)  EPIQ(x2q, 2) EPIQ(x3, 3)
    EPIQ(x4, 4)  EPIQ(x5, 5)  EPIQ(x6, 6)  EPIQ(x7, 7)
    EPIQ(x8, 8)  EPIQ(x9, 9)  EPIQ(x10,10) EPIQ(x11,11)
    EPIQ(x12,12) EPIQ(x13,13) EPIQ(x14,14) EPIQ(x15,15)

#pragma unroll
    for (int off = 32; off > 0; off >>= 1) lsum += __shfl_down(lsum, off, 64);
    const int lane = t & 63, wave = t >> 6;
    if (lane == 0) lpart[wave] = lsum;
    __syncthreads();
    if (t == 0) losspart[blockIdx.x] = ((lpart[0] + lpart[1]) + lpart[2]) + lpart[3];
}

// reduce 512 block partials (deterministic fixed-order tree) -> loss scalar
__global__ void vq_finalize_kernel(const double* __restrict__ part,
                                   float* __restrict__ out) {
    __shared__ double sdata[256];
    int t = threadIdx.x;
    sdata[t] = part[t] + part[t + 256];
    __syncthreads();
    for (int stride = 128; stride > 0; stride >>= 1) {
        if (t < stride) sdata[t] = sdata[t] + sdata[t + stride];
        __syncthreads();
    }
    if (t == 0) {
        double m = sdata[0] / (double)QST_ELEMS;
        float mf = (float)m;
        out[LOSS_OFF] = add_rn(mf, mul_rn(0.25f, mf));
    }
}

extern "C" void kernel_launch(void* const* d_in, const int* in_sizes, int n_in,
                              void* d_out, int out_size, void* d_ws, size_t ws_size,
                              hipStream_t stream) {
    const float* in  = (const float*)d_in[0];
    const float* emb = (const float*)d_in[1];
    float* out = (float*)d_out;
    char* ws = (char*)d_ws;
    double* losspart = (double*)(ws + WS_LOSS);   // 512 doubles
    float*  e2       = (float*)(ws + WS_E2);      // 512 floats
    float*  pd       = (float*)(ws + WS_PD);      // NPOS*NSPLIT floats
    int*    pi       = (int*)(ws + WS_PI);        // NPOS*NSPLIT ints

    vq_e2_kernel<<<KCODES / 64, 64, 0, stream>>>(emb, e2);
    if (ws_size >= (size_t)WS_NEED) {
        vq_scan_kernel<<<NSPLIT * PTILES, 256, 0, stream>>>(in, emb, e2, pd, pi);
        vq_epilogue_kernel<<<PTILES, 256, 0, stream>>>(in, emb, pd, pi, out, losspart);
    } else {
        vq_fused_kernel<<<PTILES, 256, 0, stream>>>(in, emb, e2, out, losspart);
    }
    vq_finalize_kernel<<<1, 256, 0, stream>>>(losspart, out);
}